// Round 1
// baseline (924.743 us; speedup 1.0000x reference)
//
#include <hip/hip_runtime.h>
#include <cstdint>

#define B_ 128
#define E_ 1024
#define R_ 64
#define T_ 4
#define IN_ 2112
#define G_ 256   // 4*R

typedef __attribute__((ext_vector_type(4))) float f32x4;
typedef __attribute__((ext_vector_type(8))) __bf16 bf16x8;

__device__ __forceinline__ unsigned short f2bf(float f) {
  unsigned int u = __float_as_uint(f);
  u += 0x7fffu + ((u >> 16) & 1u);   // RNE
  return (unsigned short)(u >> 16);
}
__device__ __forceinline__ unsigned int pack2(float lo, float hi) {
  return (unsigned int)f2bf(lo) | ((unsigned int)f2bf(hi) << 16);
}
__device__ __forceinline__ float wred_sum(float v) {
#pragma unroll
  for (int m = 32; m > 0; m >>= 1) v += __shfl_xor(v, m, 64);
  return v;
}
__device__ __forceinline__ float wred_max(float v) {
#pragma unroll
  for (int m = 32; m > 0; m >>= 1) v = fmaxf(v, __shfl_xor(v, m, 64));
  return v;
}
__device__ __forceinline__ float sigmoidf_(float x) { return 1.f / (1.f + expf(-x)); }

// ---------------- pre0 = x @ Wih0^T + bih0 + bhh0  (128x256, K=2112) -------------
__global__ __launch_bounds__(256) void pre0_kernel(
    const float* __restrict__ x, const float* __restrict__ Wih0,
    const float* __restrict__ bih0, const float* __restrict__ bhh0,
    float* __restrict__ pre0) {
  __shared__ float Wt[G_ * 65];   // 256 x 64, pad +1 to kill bank conflicts
  __shared__ float xt[8][64];
  const int tid = threadIdx.x;
  const int b0 = blockIdx.x * 8;
  float acc[8];
#pragma unroll
  for (int bb = 0; bb < 8; bb++) acc[bb] = 0.f;

  for (int j0 = 0; j0 < IN_; j0 += 64) {
    for (int l = tid; l < G_ * 16; l += 256) {      // 256 rows x 16 float4
      int g = l >> 4, c4 = (l & 15) * 4;
      const float4 v = *(const float4*)(Wih0 + g * IN_ + j0 + c4);
      float* dst = &Wt[g * 65 + c4];
      dst[0] = v.x; dst[1] = v.y; dst[2] = v.z; dst[3] = v.w;
    }
    for (int l = tid; l < 512; l += 256) {
      int bb = l >> 6, jj = l & 63;
      xt[bb][jj] = x[(b0 + bb) * IN_ + j0 + jj];
    }
    __syncthreads();
    for (int jj = 0; jj < 64; jj++) {
      float w = Wt[tid * 65 + jj];
#pragma unroll
      for (int bb = 0; bb < 8; bb++) acc[bb] += xt[bb][jj] * w;
    }
    __syncthreads();
  }
  const float bias = bih0[tid] + bhh0[tid];
#pragma unroll
  for (int bb = 0; bb < 8; bb++) pre0[(b0 + bb) * G_ + tid] = acc[bb] + bias;
}

// ---------------- LSTM recurrence (one block per batch row) + softmax/h2/att -----
__global__ __launch_bounds__(256) void recur_kernel(
    const float* __restrict__ pre0, const float* __restrict__ Whh0,
    const float* __restrict__ Wih, const float* __restrict__ Whh,
    const float* __restrict__ bih, const float* __restrict__ bhh,
    float* __restrict__ h2_out, float* __restrict__ att_out) {
  __shared__ float Wt[G_ * 65];
  __shared__ float hbuf[R_], cbuf[R_], zbuf[G_];
  __shared__ float hs_in[T_][R_], hs_out[T_][R_], hmat[T_][R_];
  const int tid = threadIdx.x;
  const int b = blockIdx.x;
  const int lane = tid & 63, wv = tid >> 6;

  auto stage_w = [&](const float* src) {
    for (int l = tid; l < G_ * 16; l += 256) {
      int g = l >> 4, c4 = (l & 15) * 4;
      const float4 v = *(const float4*)(src + g * R_ + c4);
      float* dst = &Wt[g * 65 + c4];
      dst[0] = v.x; dst[1] = v.y; dst[2] = v.z; dst[3] = v.w;
    }
  };
  auto scan = [&](float* pret) {
    for (int t = 0; t < T_; t++) {
      float z = pret[t];
#pragma unroll
      for (int j = 0; j < R_; j++) z += hbuf[j] * Wt[tid * 65 + j];
      zbuf[tid] = z;
      __syncthreads();
      if (tid < R_) {
        float iv = sigmoidf_(zbuf[tid]);
        float fv = sigmoidf_(zbuf[R_ + tid]);
        float gv = tanhf(zbuf[2 * R_ + tid]);
        float ov = sigmoidf_(zbuf[3 * R_ + tid]);
        float c = fv * cbuf[tid] + iv * gv;
        cbuf[tid] = c;
        float h = ov * tanhf(c);
        hbuf[tid] = h;
        hs_out[t][tid] = h;
      }
      __syncthreads();
    }
  };

  float pret[T_];
  {
    float p0 = pre0[b * G_ + tid];
#pragma unroll
    for (int t = 0; t < T_; t++) pret[t] = p0;
  }
  stage_w(Whh0);
  if (tid < R_) { hbuf[tid] = 0.f; cbuf[tid] = 0.f; }
  __syncthreads();
  scan(pret);

  for (int l = 0; l < T_ - 1; l++) {
    hs_in[tid >> 6][tid & 63] = hs_out[tid >> 6][tid & 63];
    __syncthreads();
    stage_w(Wih + l * G_ * R_);
    __syncthreads();
    const float bsum = bih[l * G_ + tid] + bhh[l * G_ + tid];
    for (int t = 0; t < T_; t++) {
      float p = bsum;
#pragma unroll
      for (int j = 0; j < R_; j++) p += hs_in[t][j] * Wt[tid * 65 + j];
      pret[t] = p;
    }
    __syncthreads();
    stage_w(Whh + l * G_ * R_);
    if (tid < R_) { hbuf[tid] = 0.f; cbuf[tid] = 0.f; }
    __syncthreads();
    scan(pret);
  }

  // wave wv handles timestep t = wv
  {
    float v = hs_out[wv][lane];
    float mx = wred_max(v);
    float ev = expf(v - mx);
    float sm = wred_sum(ev);
    float hval = ev / sm;                 // h = softmax(hs)
    hmat[wv][lane] = hval;
    float mx2 = wred_max(hval);
    float e2 = expf(hval - mx2);
    float s2 = wred_sum(e2);
    h2_out[(wv * B_ + b) * R_ + lane] = e2 / s2;   // h2 = softmax(h)
    __syncthreads();
    float dots[T_];
    for (int k = 0; k <= wv; k++)
      dots[k] = wred_sum(hmat[k][lane] * hmat[wv][lane]);
    if (lane == 0) {
      float mx3 = dots[0];
      for (int k = 1; k <= wv; k++) mx3 = fmaxf(mx3, dots[k]);
      float ss = 0.f, es[T_];
      for (int k = 0; k <= wv; k++) { es[k] = expf(dots[k] - mx3); ss += es[k]; }
      for (int k = 0; k <= wv; k++) att_out[(wv * B_ + b) * 4 + k] = es[k] / ss;
    }
  }
}

// ---------------- prev = sum_k att[i,b,k]*mem_k ; zero accumulator ---------------
__global__ __launch_bounds__(256) void prep_kernel(
    const float* __restrict__ x, const float* __restrict__ att,
    const float* __restrict__ mem, float* __restrict__ prev,
    float* __restrict__ newmem, int it) {
  const int idx = blockIdx.x * 256 + threadIdx.x;   // 131072 total
  const int b = idx >> 10, e = idx & 1023;
  const float* arow = att + (it * B_ + b) * 4;
  float acc = arow[0] * x[b * IN_ + R_ + e];        // mem_0 = x[:, 64:1088]
  for (int k = 1; k <= it; k++)
    acc += arow[k] * mem[(k - 1) * (B_ * E_) + b * E_ + e];
  prev[idx] = acc;
  newmem[idx] = 0.f;
}

// ---------------- big GEMM: newmem[b,e] += h2[b,r] * sum_f kb[r,e,f]*prev[b,f] ---
// grid (8 e-tiles, 64 r). Block: 128x128 tile, K=1024, 16x16x32 bf16 MFMA.
__global__ __launch_bounds__(256) void gemm_kernel(
    const float* __restrict__ prev, const float* __restrict__ h2,
    const float* __restrict__ kb, float* __restrict__ out) {
  __shared__ unsigned short As[128 * 40];   // [row=b][k], pad 32->40
  __shared__ unsigned short Bs[128 * 40];   // [row=e][k]
  __shared__ float h2s[128];
  const int tid = threadIdx.x;
  const int et = blockIdx.x;
  const int r = blockIdx.y;
  if (tid < 128) h2s[tid] = h2[tid * 64 + r];
  __syncthreads();
  const int row = tid >> 1;
  const int c0 = (tid & 1) * 16;
  const float hsc = h2s[row];
  const float* aptr = prev + row * 1024 + c0;
  const float* bptr = kb + (size_t)r * (1024u * 1024u) + (size_t)(et * 128 + row) * 1024 + c0;
  unsigned short* adst = As + row * 40 + c0;
  unsigned short* bdst = Bs + row * 40 + c0;

  const int wv = tid >> 6, lane = tid & 63;
  const int wm = (wv & 1) * 64, wn = (wv >> 1) * 64;
  const int fr = lane & 15, koff = (lane >> 4) * 8;

  f32x4 acc[4][4];
#pragma unroll
  for (int mt = 0; mt < 4; mt++)
#pragma unroll
    for (int nt = 0; nt < 4; nt++)
#pragma unroll
      for (int q = 0; q < 4; q++) acc[mt][nt][q] = 0.f;

  for (int kk = 0; kk < 32; kk++) {
    const float4 a0 = *(const float4*)(aptr + kk * 32);
    const float4 a1 = *(const float4*)(aptr + kk * 32 + 4);
    const float4 a2 = *(const float4*)(aptr + kk * 32 + 8);
    const float4 a3 = *(const float4*)(aptr + kk * 32 + 12);
    const float4 b0 = *(const float4*)(bptr + kk * 32);
    const float4 b1 = *(const float4*)(bptr + kk * 32 + 4);
    const float4 b2 = *(const float4*)(bptr + kk * 32 + 8);
    const float4 b3 = *(const float4*)(bptr + kk * 32 + 12);
    __syncthreads();   // previous iteration's fragment reads complete
    uint4 u;
    u.x = pack2(a0.x * hsc, a0.y * hsc); u.y = pack2(a0.z * hsc, a0.w * hsc);
    u.z = pack2(a1.x * hsc, a1.y * hsc); u.w = pack2(a1.z * hsc, a1.w * hsc);
    *(uint4*)adst = u;
    u.x = pack2(a2.x * hsc, a2.y * hsc); u.y = pack2(a2.z * hsc, a2.w * hsc);
    u.z = pack2(a3.x * hsc, a3.y * hsc); u.w = pack2(a3.z * hsc, a3.w * hsc);
    *(uint4*)(adst + 8) = u;
    u.x = pack2(b0.x, b0.y); u.y = pack2(b0.z, b0.w);
    u.z = pack2(b1.x, b1.y); u.w = pack2(b1.z, b1.w);
    *(uint4*)bdst = u;
    u.x = pack2(b2.x, b2.y); u.y = pack2(b2.z, b2.w);
    u.z = pack2(b3.x, b3.y); u.w = pack2(b3.z, b3.w);
    *(uint4*)(bdst + 8) = u;
    __syncthreads();
    bf16x8 af[4], bf[4];
#pragma unroll
    for (int mt = 0; mt < 4; mt++)
      af[mt] = *(const bf16x8*)(As + (wm + mt * 16 + fr) * 40 + koff);
#pragma unroll
    for (int nt = 0; nt < 4; nt++)
      bf[nt] = *(const bf16x8*)(Bs + (wn + nt * 16 + fr) * 40 + koff);
#pragma unroll
    for (int mt = 0; mt < 4; mt++)
#pragma unroll
      for (int nt = 0; nt < 4; nt++)
        acc[mt][nt] = __builtin_amdgcn_mfma_f32_16x16x32_bf16(af[mt], bf[nt], acc[mt][nt], 0, 0, 0);
  }
  // C/D layout: col = lane&15, row = (lane>>4)*4 + reg   [m89-verified]
  const int crow = (lane >> 4) * 4;
  const int ccol = et * 128 + fr;
#pragma unroll
  for (int mt = 0; mt < 4; mt++)
#pragma unroll
    for (int nt = 0; nt < 4; nt++)
#pragma unroll
      for (int q = 0; q < 4; q++)
        atomicAdd(&out[(wm + mt * 16 + crow + q) * 1024 + ccol + wn + nt * 16], acc[mt][nt][q]);
}

// ---------------- score = sigmoid(-dot(mem4, tail)) ------------------------------
__global__ __launch_bounds__(256) void score_kernel(
    const float* __restrict__ x, const float* __restrict__ mem4,
    float* __restrict__ out) {
  __shared__ float red[4];
  const int b = blockIdx.x, tid = threadIdx.x;
  float s = 0.f;
  for (int e = tid; e < E_; e += 256)
    s += mem4[b * E_ + e] * x[b * IN_ + R_ + E_ + e];
  s = wred_sum(s);
  if ((tid & 63) == 0) red[tid >> 6] = s;
  __syncthreads();
  if (tid == 0) {
    float t = red[0] + red[1] + red[2] + red[3];
    out[b] = 1.f / (1.f + expf(t));   // sigmoid(-t)
  }
}

extern "C" void kernel_launch(void* const* d_in, const int* in_sizes, int n_in,
                              void* d_out, int out_size, void* d_ws, size_t ws_size,
                              hipStream_t stream) {
  const float* x    = (const float*)d_in[0];
  const float* kb   = (const float*)d_in[1];
  const float* Wih0 = (const float*)d_in[2];
  const float* Whh0 = (const float*)d_in[3];
  const float* bih0 = (const float*)d_in[4];
  const float* bhh0 = (const float*)d_in[5];
  const float* Wih  = (const float*)d_in[6];
  const float* Whh  = (const float*)d_in[7];
  const float* bih  = (const float*)d_in[8];
  const float* bhh  = (const float*)d_in[9];
  float* ws = (float*)d_ws;
  float* pre0 = ws;                       // 32768
  float* h2   = ws + 32768;               // 4*128*64 = 32768
  float* att  = ws + 65536;               // 4*128*4  = 2048
  float* mem  = ws + 67584;               // 4*131072 (mem1..mem4)
  float* prev = ws + 67584 + 524288;      // 131072

  pre0_kernel<<<16, 256, 0, stream>>>(x, Wih0, bih0, bhh0, pre0);
  recur_kernel<<<128, 256, 0, stream>>>(pre0, Whh0, Wih, Whh, bih, bhh, h2, att);
  for (int i = 0; i < 4; i++) {
    float* newmem = mem + i * (B_ * E_);
    prep_kernel<<<512, 256, 0, stream>>>(x, att, mem, prev, newmem, i);
    gemm_kernel<<<dim3(8, 64), 256, 0, stream>>>(prev, h2 + i * (B_ * R_), kb, newmem);
  }
  score_kernel<<<128, 256, 0, stream>>>(x, mem + 3 * (B_ * E_), (float*)d_out);
}

// Round 2
// 602.019 us; speedup vs baseline: 1.5361x; 1.5361x over previous
//
#include <hip/hip_runtime.h>
#include <cstdint>
#include <cstddef>

#define B_ 128
#define E_ 1024
#define R_ 64
#define T_ 4
#define IN_ 2112
#define G_ 256   // 4*R

typedef __attribute__((ext_vector_type(4))) float f32x4;
typedef __attribute__((ext_vector_type(8))) __bf16 bf16x8;

__device__ __forceinline__ unsigned short f2bf(float f) {
  unsigned int u = __float_as_uint(f);
  u += 0x7fffu + ((u >> 16) & 1u);   // RNE
  return (unsigned short)(u >> 16);
}
__device__ __forceinline__ unsigned int pack2(float lo, float hi) {
  return (unsigned int)f2bf(lo) | ((unsigned int)f2bf(hi) << 16);
}
__device__ __forceinline__ float wred_sum(float v) {
#pragma unroll
  for (int m = 32; m > 0; m >>= 1) v += __shfl_xor(v, m, 64);
  return v;
}
__device__ __forceinline__ float wred_max(float v) {
#pragma unroll
  for (int m = 32; m > 0; m >>= 1) v = fmaxf(v, __shfl_xor(v, m, 64));
  return v;
}
__device__ __forceinline__ float sigmoidf_(float x) { return 1.f / (1.f + expf(-x)); }

__device__ __forceinline__ void gload_lds16(const void* g, void* l) {
  __builtin_amdgcn_global_load_lds(
      (const __attribute__((address_space(1))) unsigned int*)g,
      (__attribute__((address_space(3))) unsigned int*)l, 16, 0, 0);
}

// ============ head: blocks [0,128) = LSTM recurrence (+fused pre0);
// ============        blocks >=128  = kb fp32->bf16 conversion (overlapped)
__global__ __launch_bounds__(256) void head_kernel(
    const float* __restrict__ x, const float* __restrict__ kb,
    const float* __restrict__ Wih0, const float* __restrict__ Whh0,
    const float* __restrict__ bih0, const float* __restrict__ bhh0,
    const float* __restrict__ Wih, const float* __restrict__ Whh,
    const float* __restrict__ bih, const float* __restrict__ bhh,
    unsigned short* __restrict__ kb_bf,
    float* __restrict__ h2_out, float* __restrict__ att_out) {
  __shared__ float Wt[G_ * 65];
  __shared__ float xrow[IN_];
  __shared__ float hbuf[R_], cbuf[R_], zbuf[G_];
  __shared__ float hs_in[T_][R_], hs_out[T_][R_], hmat[T_][R_];
  const int tid = threadIdx.x;

  if (blockIdx.x >= 128) {
    // ---- kb conversion: 64Mi elems over 8192 blocks, 32 elems/thread ----
    const size_t base = (size_t)(blockIdx.x - 128) * 8192;
#pragma unroll
    for (int c = 0; c < 4; c++) {
      size_t o = base + (size_t)c * 2048 + (size_t)tid * 8;
      float4 v0 = *(const float4*)(kb + o);
      float4 v1 = *(const float4*)(kb + o + 4);
      uint4 u;
      u.x = pack2(v0.x, v0.y); u.y = pack2(v0.z, v0.w);
      u.z = pack2(v1.x, v1.y); u.w = pack2(v1.z, v1.w);
      *(uint4*)(kb_bf + o) = u;
    }
    return;
  }

  const int b = blockIdx.x;
  const int lane = tid & 63, wv = tid >> 6;

  // ---- fused pre0: stage x row, each thread g dots x[b,:].Wih0[g,:] ----
  for (int l = tid; l < IN_; l += 256) xrow[l] = x[b * IN_ + l];
  __syncthreads();
  float p0 = bih0[tid] + bhh0[tid];
  {
    const float* wr = Wih0 + (size_t)tid * IN_;
#pragma unroll 4
    for (int j = 0; j < IN_; j += 4) {
      float4 w = *(const float4*)(wr + j);
      p0 += xrow[j] * w.x + xrow[j + 1] * w.y + xrow[j + 2] * w.z + xrow[j + 3] * w.w;
    }
  }

  auto stage_w = [&](const float* src) {
    for (int l = tid; l < G_ * 16; l += 256) {
      int g = l >> 4, c4 = (l & 15) * 4;
      const float4 v = *(const float4*)(src + g * R_ + c4);
      float* dst = &Wt[g * 65 + c4];
      dst[0] = v.x; dst[1] = v.y; dst[2] = v.z; dst[3] = v.w;
    }
  };
  auto scan = [&](float* pret) {
    for (int t = 0; t < T_; t++) {
      float z = pret[t];
#pragma unroll
      for (int j = 0; j < R_; j++) z += hbuf[j] * Wt[tid * 65 + j];
      zbuf[tid] = z;
      __syncthreads();
      if (tid < R_) {
        float iv = sigmoidf_(zbuf[tid]);
        float fv = sigmoidf_(zbuf[R_ + tid]);
        float gv = tanhf(zbuf[2 * R_ + tid]);
        float ov = sigmoidf_(zbuf[3 * R_ + tid]);
        float c = fv * cbuf[tid] + iv * gv;
        cbuf[tid] = c;
        float h = ov * tanhf(c);
        hbuf[tid] = h;
        hs_out[t][tid] = h;
      }
      __syncthreads();
    }
  };

  float pret[T_];
#pragma unroll
  for (int t = 0; t < T_; t++) pret[t] = p0;
  stage_w(Whh0);
  if (tid < R_) { hbuf[tid] = 0.f; cbuf[tid] = 0.f; }
  __syncthreads();
  scan(pret);

  for (int l = 0; l < T_ - 1; l++) {
    hs_in[tid >> 6][tid & 63] = hs_out[tid >> 6][tid & 63];
    __syncthreads();
    stage_w(Wih + l * G_ * R_);
    __syncthreads();
    const float bsum = bih[l * G_ + tid] + bhh[l * G_ + tid];
    for (int t = 0; t < T_; t++) {
      float p = bsum;
#pragma unroll
      for (int j = 0; j < R_; j++) p += hs_in[t][j] * Wt[tid * 65 + j];
      pret[t] = p;
    }
    __syncthreads();
    stage_w(Whh + l * G_ * R_);
    if (tid < R_) { hbuf[tid] = 0.f; cbuf[tid] = 0.f; }
    __syncthreads();
    scan(pret);
  }

  // wave wv handles timestep t = wv
  {
    float v = hs_out[wv][lane];
    float mx = wred_max(v);
    float ev = expf(v - mx);
    float sm = wred_sum(ev);
    float hval = ev / sm;                 // h = softmax(hs)
    hmat[wv][lane] = hval;
    float mx2 = wred_max(hval);
    float e2 = expf(hval - mx2);
    float s2 = wred_sum(e2);
    h2_out[(wv * B_ + b) * R_ + lane] = e2 / s2;   // h2 = softmax(h)
    __syncthreads();
    float dots[T_];
    for (int k = 0; k <= wv; k++)
      dots[k] = wred_sum(hmat[k][lane] * hmat[wv][lane]);
    if (lane == 0) {
      float mx3 = dots[0];
      for (int k = 1; k <= wv; k++) mx3 = fmaxf(mx3, dots[k]);
      float ss = 0.f, es[T_];
      for (int k = 0; k <= wv; k++) { es[k] = expf(dots[k] - mx3); ss += es[k]; }
      for (int k = 0; k <= wv; k++) att_out[(wv * B_ + b) * 4 + k] = es[k] / ss;
    }
  }
}

// ============ prev for pass 0: prev = att[0,b,0] * x[:,64:1088] (bf16) ============
__global__ __launch_bounds__(256) void prep0_kernel(
    const float* __restrict__ x, const float* __restrict__ att,
    unsigned short* __restrict__ prev_bf) {
  const int idx = blockIdx.x * 256 + threadIdx.x;   // 131072
  const int b = idx >> 10, e = idx & 1023;
  float a0 = att[b * 4];   // att row 0, entry 0 (==1.0)
  prev_bf[idx] = f2bf(a0 * x[b * IN_ + R_ + e]);
}

// ============ GEMM: part[r][b][e] = sum_f prev[b,f]*kb[r,e,f]  (bf16 MFMA) =======
// grid (8 e-tiles, 64 r), block 256. Tile 128x128, K=1024, global_load_lds staging.
__global__ __launch_bounds__(256) void gemm_bf_kernel(
    const unsigned short* __restrict__ Abf,   // [128][1024] bf16
    const unsigned short* __restrict__ Kbf,   // [64][1024][1024] bf16
    float* __restrict__ part) {               // [64][128][1024]
  __shared__ unsigned short As[128 * 32];
  __shared__ unsigned short Bs[128 * 32];
  const int tid = threadIdx.x, wv = tid >> 6, lane = tid & 63;
  const int et = blockIdx.x, r = blockIdx.y;
  const int wm = (wv & 1) * 64, wn = (wv >> 1) * 64;
  const int fr = lane & 15, koff = (lane >> 4) * 8;

  // staging: wave wv covers rows [wv*32, wv*32+32), two 16-row instructions
  const int srow = wv * 32 + (lane >> 2);
  const int scol = (lane & 3) * 8;
  const unsigned short* agp = Abf + (size_t)srow * 1024 + scol;
  const unsigned short* bgp = Kbf + (size_t)r * 1048576 + (size_t)(et * 128 + srow) * 1024 + scol;
  unsigned short* a_l0 = As + wv * 1024;
  unsigned short* a_l1 = As + wv * 1024 + 512;
  unsigned short* b_l0 = Bs + wv * 1024;
  unsigned short* b_l1 = Bs + wv * 1024 + 512;

  f32x4 acc[4][4];
#pragma unroll
  for (int mt = 0; mt < 4; mt++)
#pragma unroll
    for (int nt = 0; nt < 4; nt++)
#pragma unroll
      for (int q = 0; q < 4; q++) acc[mt][nt][q] = 0.f;

  for (int kk = 0; kk < 32; kk++) {
    gload_lds16(agp + kk * 32,             a_l0);
    gload_lds16(agp + kk * 32 + 16 * 1024, a_l1);
    gload_lds16(bgp + kk * 32,             b_l0);
    gload_lds16(bgp + kk * 32 + 16 * 1024, b_l1);
    __syncthreads();   // vmcnt(0) drain -> tiles resident
    bf16x8 af[4], bfr[4];
#pragma unroll
    for (int mt = 0; mt < 4; mt++)
      af[mt] = *(const bf16x8*)(As + (wm + mt * 16 + fr) * 32 + koff);
#pragma unroll
    for (int nt = 0; nt < 4; nt++)
      bfr[nt] = *(const bf16x8*)(Bs + (wn + nt * 16 + fr) * 32 + koff);
#pragma unroll
    for (int mt = 0; mt < 4; mt++)
#pragma unroll
      for (int nt = 0; nt < 4; nt++)
        acc[mt][nt] = __builtin_amdgcn_mfma_f32_16x16x32_bf16(af[mt], bfr[nt], acc[mt][nt], 0, 0, 0);
    __syncthreads();   // fragment reads done before next staging
  }
  // C/D: col = lane&15, row = (lane>>4)*4 + q
  const int crow = (lane >> 4) * 4;
  float* pout = part + (size_t)r * 131072;
#pragma unroll
  for (int mt = 0; mt < 4; mt++)
#pragma unroll
    for (int nt = 0; nt < 4; nt++)
#pragma unroll
      for (int q = 0; q < 4; q++)
        pout[(wm + mt * 16 + crow + q) * 1024 + et * 128 + wn + nt * 16 + fr] = acc[mt][nt][q];
}

// ============ mid: mem_it = sum_r h2[it,b,r]*part[r,b,e]; prep next prev ========
__global__ __launch_bounds__(256) void mid_kernel(
    const float* __restrict__ part, const float* __restrict__ h2,
    const float* __restrict__ att, const float* __restrict__ x,
    float* __restrict__ mem, unsigned short* __restrict__ prev_bf, int it) {
  const int idx = blockIdx.x * 256 + threadIdx.x;   // 131072
  const int b = idx >> 10, e = idx & 1023;
  const float* h2row = h2 + (it * B_ + b) * R_;     // b uniform per block
  const float* pp = part + idx;
  float s = 0.f;
#pragma unroll 8
  for (int rr = 0; rr < 64; rr++) s += h2row[rr] * pp[(size_t)rr * 131072];
  mem[it * 131072 + idx] = s;
  if (it < 3) {
    const float* arow = att + ((it + 1) * B_ + b) * 4;
    float acc = arow[0] * x[b * IN_ + R_ + e];
    for (int k = 1; k <= it; k++) acc += arow[k] * mem[(k - 1) * 131072 + idx];
    acc += arow[it + 1] * s;
    prev_bf[idx] = f2bf(acc);
  }
}

// ============ fallback path (small ws): round-0 fp32-kb gemm ====================
__global__ __launch_bounds__(256) void prep_fp32_kernel(
    const float* __restrict__ x, const float* __restrict__ att,
    const float* __restrict__ mem, float* __restrict__ prev,
    float* __restrict__ newmem, int it) {
  const int idx = blockIdx.x * 256 + threadIdx.x;
  const int b = idx >> 10, e = idx & 1023;
  const float* arow = att + (it * B_ + b) * 4;
  float acc = arow[0] * x[b * IN_ + R_ + e];
  for (int k = 1; k <= it; k++)
    acc += arow[k] * mem[(k - 1) * (B_ * E_) + b * E_ + e];
  prev[idx] = acc;
  newmem[idx] = 0.f;
}

__global__ __launch_bounds__(256) void gemm_fp32_kernel(
    const float* __restrict__ prev, const float* __restrict__ h2,
    const float* __restrict__ kb, float* __restrict__ out) {
  __shared__ unsigned short As[128 * 40];
  __shared__ unsigned short Bs[128 * 40];
  __shared__ float h2s[128];
  const int tid = threadIdx.x;
  const int et = blockIdx.x;
  const int r = blockIdx.y;
  if (tid < 128) h2s[tid] = h2[tid * 64 + r];
  __syncthreads();
  const int row = tid >> 1;
  const int c0 = (tid & 1) * 16;
  const float hsc = h2s[row];
  const float* aptr = prev + row * 1024 + c0;
  const float* bptr = kb + (size_t)r * (1024u * 1024u) + (size_t)(et * 128 + row) * 1024 + c0;
  unsigned short* adst = As + row * 40 + c0;
  unsigned short* bdst = Bs + row * 40 + c0;
  const int wv = tid >> 6, lane = tid & 63;
  const int wm = (wv & 1) * 64, wn = (wv >> 1) * 64;
  const int fr = lane & 15, koff = (lane >> 4) * 8;
  f32x4 acc[4][4];
#pragma unroll
  for (int mt = 0; mt < 4; mt++)
#pragma unroll
    for (int nt = 0; nt < 4; nt++)
#pragma unroll
      for (int q = 0; q < 4; q++) acc[mt][nt][q] = 0.f;
  for (int kk = 0; kk < 32; kk++) {
    const float4 a0 = *(const float4*)(aptr + kk * 32);
    const float4 a1 = *(const float4*)(aptr + kk * 32 + 4);
    const float4 a2 = *(const float4*)(aptr + kk * 32 + 8);
    const float4 a3 = *(const float4*)(aptr + kk * 32 + 12);
    const float4 b0 = *(const float4*)(bptr + kk * 32);
    const float4 b1 = *(const float4*)(bptr + kk * 32 + 4);
    const float4 b2 = *(const float4*)(bptr + kk * 32 + 8);
    const float4 b3 = *(const float4*)(bptr + kk * 32 + 12);
    __syncthreads();
    uint4 u;
    u.x = pack2(a0.x * hsc, a0.y * hsc); u.y = pack2(a0.z * hsc, a0.w * hsc);
    u.z = pack2(a1.x * hsc, a1.y * hsc); u.w = pack2(a1.z * hsc, a1.w * hsc);
    *(uint4*)adst = u;
    u.x = pack2(a2.x * hsc, a2.y * hsc); u.y = pack2(a2.z * hsc, a2.w * hsc);
    u.z = pack2(a3.x * hsc, a3.y * hsc); u.w = pack2(a3.z * hsc, a3.w * hsc);
    *(uint4*)(adst + 8) = u;
    u.x = pack2(b0.x, b0.y); u.y = pack2(b0.z, b0.w);
    u.z = pack2(b1.x, b1.y); u.w = pack2(b1.z, b1.w);
    *(uint4*)bdst = u;
    u.x = pack2(b2.x, b2.y); u.y = pack2(b2.z, b2.w);
    u.z = pack2(b3.x, b3.y); u.w = pack2(b3.z, b3.w);
    *(uint4*)(bdst + 8) = u;
    __syncthreads();
    bf16x8 af[4], bfr[4];
#pragma unroll
    for (int mt = 0; mt < 4; mt++)
      af[mt] = *(const bf16x8*)(As + (wm + mt * 16 + fr) * 40 + koff);
#pragma unroll
    for (int nt = 0; nt < 4; nt++)
      bfr[nt] = *(const bf16x8*)(Bs + (wn + nt * 16 + fr) * 40 + koff);
#pragma unroll
    for (int mt = 0; mt < 4; mt++)
#pragma unroll
      for (int nt = 0; nt < 4; nt++)
        acc[mt][nt] = __builtin_amdgcn_mfma_f32_16x16x32_bf16(af[mt], bfr[nt], acc[mt][nt], 0, 0, 0);
  }
  const int crow = (lane >> 4) * 4;
  const int ccol = et * 128 + fr;
#pragma unroll
  for (int mt = 0; mt < 4; mt++)
#pragma unroll
    for (int nt = 0; nt < 4; nt++)
#pragma unroll
      for (int q = 0; q < 4; q++)
        atomicAdd(&out[(wm + mt * 16 + crow + q) * 1024 + ccol + wn + nt * 16], acc[mt][nt][q]);
}

// ============ score = sigmoid(-dot(mem4, tail)) =================================
__global__ __launch_bounds__(256) void score_kernel(
    const float* __restrict__ x, const float* __restrict__ mem4,
    float* __restrict__ out) {
  __shared__ float red[4];
  const int b = blockIdx.x, tid = threadIdx.x;
  float s = 0.f;
  for (int e = tid; e < E_; e += 256)
    s += mem4[b * E_ + e] * x[b * IN_ + R_ + E_ + e];
  s = wred_sum(s);
  if ((tid & 63) == 0) red[tid >> 6] = s;
  __syncthreads();
  if (tid == 0) {
    float t = red[0] + red[1] + red[2] + red[3];
    out[b] = 1.f / (1.f + expf(t));   // sigmoid(-t)
  }
}

extern "C" void kernel_launch(void* const* d_in, const int* in_sizes, int n_in,
                              void* d_out, int out_size, void* d_ws, size_t ws_size,
                              hipStream_t stream) {
  const float* x    = (const float*)d_in[0];
  const float* kb   = (const float*)d_in[1];
  const float* Wih0 = (const float*)d_in[2];
  const float* Whh0 = (const float*)d_in[3];
  const float* bih0 = (const float*)d_in[4];
  const float* bhh0 = (const float*)d_in[5];
  const float* Wih  = (const float*)d_in[6];
  const float* Whh  = (const float*)d_in[7];
  const float* bih  = (const float*)d_in[8];
  const float* bhh  = (const float*)d_in[9];

  float* ws    = (float*)d_ws;
  float* h2    = ws;                    // 32768
  float* att   = ws + 32768;            // 2048
  float* mem   = ws + 34816;            // 4*131072
  float* prevb = ws + 559104;           // 131072 (bf16 or fp32 prev)
  float* part  = ws + 690176;           // 64*131072 = 8388608
  float* kbbf  = ws + 9078784;          // 33554432 (64Mi bf16)
  const size_t need_big = (size_t)(9078784 + 33554432) * sizeof(float);  // ~170.5 MB
  const bool big = ws_size >= need_big;

  if (big) {
    head_kernel<<<8320, 256, 0, stream>>>(x, kb, Wih0, Whh0, bih0, bhh0,
                                          Wih, Whh, bih, bhh,
                                          (unsigned short*)kbbf, h2, att);
    prep0_kernel<<<512, 256, 0, stream>>>(x, att, (unsigned short*)prevb);
    for (int i = 0; i < 4; i++) {
      gemm_bf_kernel<<<dim3(8, 64), 256, 0, stream>>>(
          (const unsigned short*)prevb, (const unsigned short*)kbbf, part);
      mid_kernel<<<512, 256, 0, stream>>>(part, h2, att, x, mem,
                                          (unsigned short*)prevb, i);
    }
  } else {
    head_kernel<<<128, 256, 0, stream>>>(x, kb, Wih0, Whh0, bih0, bhh0,
                                         Wih, Whh, bih, bhh,
                                         (unsigned short*)prevb /*unused*/, h2, att);
    for (int i = 0; i < 4; i++) {
      float* newmem = mem + i * (B_ * E_);
      prep_fp32_kernel<<<512, 256, 0, stream>>>(x, att, mem, prevb, newmem, i);
      gemm_fp32_kernel<<<dim3(8, 64), 256, 0, stream>>>(prevb, h2 + i * (B_ * R_), kb, newmem);
    }
  }
  score_kernel<<<128, 256, 0, stream>>>(x, mem + 3 * (B_ * E_), (float*)d_out);
}